// Round 2
// baseline (910.849 us; speedup 1.0000x reference)
//
#include <hip/hip_runtime.h>

#define D_MODEL 2048
#define S_LEN 2048
#define NB 2
#define NH 16
#define DK 128

typedef __attribute__((ext_vector_type(8))) __bf16 bf16x8;
typedef __attribute__((ext_vector_type(4))) float f32x4;

__device__ __forceinline__ unsigned short f2bf(float f) {
    unsigned int u = __float_as_uint(f);
    return (unsigned short)((u + 0x7fffu + ((u >> 16) & 1u)) >> 16);
}

__device__ __forceinline__ void gld_lds16(const void* g, void* l) {
    __builtin_amdgcn_global_load_lds(
        (const __attribute__((address_space(1))) unsigned int*)g,
        (__attribute__((address_space(3))) unsigned int*)l, 16, 0, 0);
}

__global__ void cast_f32_to_bf16(const float* __restrict__ x,
                                 unsigned short* __restrict__ y, int n4) {
    int i = blockIdx.x * blockDim.x + threadIdx.x;
    int stride = gridDim.x * blockDim.x;
    const float4* x4 = (const float4*)x;
    ushort4* y4 = (ushort4*)y;
    for (; i < n4; i += stride) {
        float4 v = x4[i];
        ushort4 o;
        o.x = f2bf(v.x); o.y = f2bf(v.y); o.z = f2bf(v.z); o.w = f2bf(v.w);
        y4[i] = o;
    }
}

// ---------------- GEMM (m97 structure): C[m,n] = sum_k A[m,k]*Bt[n,k] -------
#define BM 128
#define BN 128
#define BK 64

__device__ __forceinline__ void cstore(float* p, float v) { *p = v; }
__device__ __forceinline__ void cstore(unsigned short* p, float v) { *p = f2bf(v); }

template <typename OutT>
__global__ __launch_bounds__(256) void gemm_bt(const unsigned short* __restrict__ A,
                                               const unsigned short* __restrict__ Bt,
                                               OutT* __restrict__ C,
                                               int M, int N, int K) {
    // no padding: global_load_lds requires base + lane*16B contiguous layout
    __shared__ __align__(16) unsigned short As[BM * BK];
    __shared__ __align__(16) unsigned short Bs[BN * BK];
    const int tid = threadIdx.x;
    const int lane = tid & 63;
    const int wave = tid >> 6;
    const int quad = lane >> 4;
    const int l15 = lane & 15;
    const int wr = (wave >> 1) * 64;
    const int wc = (wave & 1) * 64;
    const int m0 = blockIdx.x * BM;
    const int n0 = blockIdx.y * BN;

    // staging map: wave covers rows [wave*32, wave*32+32), 8 rows per call
    const int srow = wave * 32 + (lane >> 3);
    const int skc = (lane & 7) * 8;

    f32x4 zero = {0.f, 0.f, 0.f, 0.f};
    f32x4 acc[4][4];
    for (int i = 0; i < 4; i++)
        for (int j = 0; j < 4; j++) acc[i][j] = zero;

    for (int k0 = 0; k0 < K; k0 += BK) {
        __syncthreads();
        const unsigned short* Ag = A + (size_t)(m0 + srow) * K + k0 + skc;
        const unsigned short* Bg = Bt + (size_t)(n0 + srow) * K + k0 + skc;
        unsigned short* Al = &As[srow * BK + skc];
        unsigned short* Bl = &Bs[srow * BK + skc];
#pragma unroll
        for (int t = 0; t < 4; t++) {
            gld_lds16(Ag + (size_t)t * 8 * K, Al + t * 8 * BK);
            gld_lds16(Bg + (size_t)t * 8 * K, Bl + t * 8 * BK);
        }
        __syncthreads();  // compiler emits vmcnt(0) drain here

        bf16x8 af[4][2], bfr[4][2];
#pragma unroll
        for (int t = 0; t < 4; t++)
#pragma unroll
            for (int c = 0; c < 2; c++) {
                af[t][c]  = *(const bf16x8*)(&As[(wr + t * 16 + l15) * BK + c * 32 + quad * 8]);
                bfr[t][c] = *(const bf16x8*)(&Bs[(wc + t * 16 + l15) * BK + c * 32 + quad * 8]);
            }
#pragma unroll
        for (int c = 0; c < 2; c++)
#pragma unroll
            for (int mt = 0; mt < 4; mt++)
#pragma unroll
                for (int nt = 0; nt < 4; nt++)
                    acc[mt][nt] = __builtin_amdgcn_mfma_f32_16x16x32_bf16(
                        af[mt][c], bfr[nt][c], acc[mt][nt], 0, 0, 0);
    }

#pragma unroll
    for (int mt = 0; mt < 4; mt++)
#pragma unroll
        for (int nt = 0; nt < 4; nt++)
#pragma unroll
            for (int r = 0; r < 4; r++) {
                int m = m0 + wr + mt * 16 + quad * 4 + r;
                int n = n0 + wc + nt * 16 + l15;
                cstore(&C[(size_t)m * N + n], acc[mt][nt][r]);
            }
}

// ---------------- Flash attention, zero-barrier, static-max softcap ---------
#define PS_STRIDE 88  // 64 + 24 pad: 176B rows (16B-mult), 2-way banks on b128 reads

__global__ __launch_bounds__(256) void flash_attn(
        const unsigned short* __restrict__ Q,
        const unsigned short* __restrict__ K,
        const unsigned short* __restrict__ Vt,   // [D_MODEL][NB*S_LEN]  (= V^T)
        const float* __restrict__ bias,
        const int* __restrict__ softcap,
        unsigned short* __restrict__ O) {
    __shared__ __align__(16) unsigned short Ps[4 * 16 * PS_STRIDE];

    const int tid = threadIdx.x;
    const int lane = tid & 63;
    const int wave = tid >> 6;
    const int quad = lane >> 4;
    const int l15 = lane & 15;
    const int q0 = blockIdx.x * 64;
    const int h = blockIdx.y;
    const int b = blockIdx.z;

    const float scale = 0.08838834764831845f;  // 1/sqrt(128)
    const float cap = (float)softcap[0];
    const float LOG2E = 1.4426950408889634f;
    const float c1 = 2.0f * LOG2E * scale / cap;  // score coeff  -> exp2 arg
    const float c2 = 2.0f * LOG2E / cap;          // bias coeff
    const float c3 = -2.0f * cap * LOG2E;         // exp2(c3 * rcp(u+1)) = p

    const size_t head_off = (size_t)b * S_LEN * D_MODEL + (size_t)h * DK;
    const size_t vt_row = (size_t)NB * S_LEN;
    const unsigned short* Vh = Vt + (size_t)h * DK * vt_row + (size_t)b * S_LEN;

    // Q fragments (A-layout): 16 q-rows per wave
    bf16x8 qf[4];
    {
        const unsigned short* Qp = Q + head_off + (size_t)(q0 + wave * 16 + l15) * D_MODEL;
#pragma unroll
        for (int c = 0; c < 4; c++)
            qf[c] = *(const bf16x8*)(Qp + c * 32 + quad * 8);
    }

    f32x4 zero = {0.f, 0.f, 0.f, 0.f};
    float l_part[4] = {0.f, 0.f, 0.f, 0.f};
    f32x4 o_acc[8];
#pragma unroll
    for (int d = 0; d < 8; d++) o_acc[d] = zero;

    unsigned short* Psw = &Ps[wave * 16 * PS_STRIDE];
    const int qrow = q0 + wave * 16 + quad * 4;

    for (int kt = 0; kt < S_LEN / 64; kt++) {
        const int kbase = kt * 64;

        // ---- S = Q K^T (16x64 per wave), K fragments direct from global ----
        f32x4 s[4];
#pragma unroll
        for (int nt = 0; nt < 4; nt++) s[nt] = zero;
#pragma unroll
        for (int c = 0; c < 4; c++) {
            bf16x8 kf[4];
#pragma unroll
            for (int nt = 0; nt < 4; nt++)
                kf[nt] = *(const bf16x8*)(K + head_off +
                    (size_t)(kbase + nt * 16 + l15) * D_MODEL + c * 32 + quad * 8);
#pragma unroll
            for (int nt = 0; nt < 4; nt++)
                s[nt] = __builtin_amdgcn_mfma_f32_16x16x32_bf16(qf[c], kf[nt], s[nt], 0, 0, 0);
        }

        // ---- fused softcap+softmax: p = exp(cap*tanh(x/cap) - cap) --------
        //      = exp2(c3 / (exp2(c1*s + c2*bias) + 1));  static max = cap.
#pragma unroll
        for (int nt = 0; nt < 4; nt++) {
            const float* bp = bias + (size_t)qrow * S_LEN + kbase + nt * 16 + l15;
#pragma unroll
            for (int r = 0; r < 4; r++) {
                float arg = fmaf(s[nt][r], c1, bp[(size_t)r * S_LEN] * c2);
                float u = __builtin_amdgcn_exp2f(arg);
                float p = __builtin_amdgcn_exp2f(c3 * __builtin_amdgcn_rcpf(u + 1.0f));
                s[nt][r] = p;
                l_part[r] += p;
            }
        }

        // ---- P: C-layout -> per-wave LDS -> A-layout (no barrier needed) --
#pragma unroll
        for (int nt = 0; nt < 4; nt++)
#pragma unroll
            for (int r = 0; r < 4; r++)
                Psw[(quad * 4 + r) * PS_STRIDE + nt * 16 + l15] = f2bf(s[nt][r]);

        // ---- O += P V, V^T fragments direct from global -------------------
#pragma unroll
        for (int c = 0; c < 2; c++) {
            bf16x8 pf = *(const bf16x8*)(&Psw[l15 * PS_STRIDE + c * 32 + quad * 8]);
#pragma unroll
            for (int dt = 0; dt < 8; dt++) {
                bf16x8 vf = *(const bf16x8*)(Vh +
                    (size_t)(dt * 16 + l15) * vt_row + kbase + c * 32 + quad * 8);
                o_acc[dt] = __builtin_amdgcn_mfma_f32_16x16x32_bf16(pf, vf, o_acc[dt], 0, 0, 0);
            }
        }
    }

    // ---- finalize: reduce l across the 16 lanes sharing each row, write ---
#pragma unroll
    for (int r = 0; r < 4; r++) {
        float l = l_part[r];
        l += __shfl_xor(l, 1, 64);
        l += __shfl_xor(l, 2, 64);
        l += __shfl_xor(l, 4, 64);
        l += __shfl_xor(l, 8, 64);
        float inv = 1.0f / l;
        int row = qrow + r;
        unsigned short* Op = O + (size_t)(b * S_LEN + row) * D_MODEL + h * DK;
#pragma unroll
        for (int dt = 0; dt < 8; dt++)
            Op[dt * 16 + l15] = f2bf(o_acc[dt][r] * inv);
    }
}

// ---------------- host ----------------
extern "C" void kernel_launch(void* const* d_in, const int* in_sizes, int n_in,
                              void* d_out, int out_size, void* d_ws, size_t ws_size,
                              hipStream_t stream) {
    const float* inp = (const float*)d_in[0];
    const float* wq  = (const float*)d_in[1];
    const float* wk  = (const float*)d_in[2];
    const float* wv  = (const float*)d_in[3];
    const float* wo  = (const float*)d_in[4];
    const float* bias = (const float*)d_in[5];
    const int* softcap = (const int*)d_in[6];
    float* out = (float*)d_out;

    unsigned short* ws = (unsigned short*)d_ws;
    const size_t n_inp = (size_t)NB * S_LEN * D_MODEL;  // 8,388,608
    const size_t n_w = (size_t)D_MODEL * D_MODEL;       // 4,194,304
    unsigned short* inp_b = ws;
    unsigned short* wq_b = inp_b + n_inp;
    unsigned short* wk_b = wq_b + n_w;
    unsigned short* wv_b = wk_b + n_w;
    unsigned short* wo_b = wv_b + n_w;
    unsigned short* Qb = wo_b + n_w;
    unsigned short* Kb = Qb + n_inp;
    unsigned short* Vtb = Kb + n_inp;   // [D_MODEL][NB*S_LEN] = V^T
    unsigned short* Ob = Vtb + n_inp;

    cast_f32_to_bf16<<<dim3(1024), dim3(256), 0, stream>>>(inp, inp_b, (int)(n_inp / 4));
    cast_f32_to_bf16<<<dim3(512), dim3(256), 0, stream>>>(wq, wq_b, (int)(n_w / 4));
    cast_f32_to_bf16<<<dim3(512), dim3(256), 0, stream>>>(wk, wk_b, (int)(n_w / 4));
    cast_f32_to_bf16<<<dim3(512), dim3(256), 0, stream>>>(wv, wv_b, (int)(n_w / 4));
    cast_f32_to_bf16<<<dim3(512), dim3(256), 0, stream>>>(wo, wo_b, (int)(n_w / 4));

    dim3 gg(NB * S_LEN / BM, D_MODEL / BN);  // (32, 16)
    gemm_bt<unsigned short><<<gg, 256, 0, stream>>>(inp_b, wq_b, Qb, NB * S_LEN, D_MODEL, D_MODEL);
    gemm_bt<unsigned short><<<gg, 256, 0, stream>>>(inp_b, wk_b, Kb, NB * S_LEN, D_MODEL, D_MODEL);
    // V^T = Wv * X^T : same kernel, swapped operands -> output [D_MODEL][NB*S]
    dim3 gv(D_MODEL / BM, NB * S_LEN / BN);  // (16, 32)
    gemm_bt<unsigned short><<<gv, 256, 0, stream>>>(wv_b, inp_b, Vtb, D_MODEL, NB * S_LEN, D_MODEL);

    flash_attn<<<dim3(S_LEN / 64, NH, NB), 256, 0, stream>>>(Qb, Kb, Vtb, bias, softcap, Ob);

    gemm_bt<float><<<gg, 256, 0, stream>>>(Ob, wo_b, out, NB * S_LEN, D_MODEL, D_MODEL);
}

// Round 3
// 707.948 us; speedup vs baseline: 1.2866x; 1.2866x over previous
//
#include <hip/hip_runtime.h>

#define D_MODEL 2048
#define S_LEN 2048
#define NB 2
#define NH 16
#define DK 128

typedef __attribute__((ext_vector_type(8))) __bf16 bf16x8;
typedef __attribute__((ext_vector_type(4))) float f32x4;

__device__ __forceinline__ unsigned short f2bf(float f) {
    unsigned int u = __float_as_uint(f);
    return (unsigned short)((u + 0x7fffu + ((u >> 16) & 1u)) >> 16);
}

__device__ __forceinline__ void gld_lds16(const void* g, void* l) {
    __builtin_amdgcn_global_load_lds(
        (const __attribute__((address_space(1))) unsigned int*)g,
        (__attribute__((address_space(3))) unsigned int*)l, 16, 0, 0);
}

__global__ void cast_f32_to_bf16(const float* __restrict__ x,
                                 unsigned short* __restrict__ y, int n4) {
    int i = blockIdx.x * blockDim.x + threadIdx.x;
    int stride = gridDim.x * blockDim.x;
    const float4* x4 = (const float4*)x;
    ushort4* y4 = (ushort4*)y;
    for (; i < n4; i += stride) {
        float4 v = x4[i];
        ushort4 o;
        o.x = f2bf(v.x); o.y = f2bf(v.y); o.z = f2bf(v.z); o.w = f2bf(v.w);
        y4[i] = o;
    }
}

// ---------------- GEMM (m97 structure): C[m,n] = sum_k A[m,k]*Bt[n,k] -------
#define BM 128
#define BN 128
#define BK 64

__device__ __forceinline__ void cstore(float* p, float v) { *p = v; }
__device__ __forceinline__ void cstore(unsigned short* p, float v) { *p = f2bf(v); }

template <typename OutT>
__global__ __launch_bounds__(256) void gemm_bt(const unsigned short* __restrict__ A,
                                               const unsigned short* __restrict__ Bt,
                                               OutT* __restrict__ C,
                                               int M, int N, int K) {
    __shared__ __align__(16) unsigned short As[BM * BK];
    __shared__ __align__(16) unsigned short Bs[BN * BK];
    const int tid = threadIdx.x;
    const int lane = tid & 63;
    const int wave = tid >> 6;
    const int quad = lane >> 4;
    const int l15 = lane & 15;
    const int wr = (wave >> 1) * 64;
    const int wc = (wave & 1) * 64;
    const int m0 = blockIdx.x * BM;
    const int n0 = blockIdx.y * BN;

    const int srow = wave * 32 + (lane >> 3);
    const int skc = (lane & 7) * 8;

    f32x4 zero = {0.f, 0.f, 0.f, 0.f};
    f32x4 acc[4][4];
    for (int i = 0; i < 4; i++)
        for (int j = 0; j < 4; j++) acc[i][j] = zero;

    for (int k0 = 0; k0 < K; k0 += BK) {
        __syncthreads();
        const unsigned short* Ag = A + (size_t)(m0 + srow) * K + k0 + skc;
        const unsigned short* Bg = Bt + (size_t)(n0 + srow) * K + k0 + skc;
        unsigned short* Al = &As[srow * BK + skc];
        unsigned short* Bl = &Bs[srow * BK + skc];
#pragma unroll
        for (int t = 0; t < 4; t++) {
            gld_lds16(Ag + (size_t)t * 8 * K, Al + t * 8 * BK);
            gld_lds16(Bg + (size_t)t * 8 * K, Bl + t * 8 * BK);
        }
        __syncthreads();

        bf16x8 af[4][2], bfr[4][2];
#pragma unroll
        for (int t = 0; t < 4; t++)
#pragma unroll
            for (int c = 0; c < 2; c++) {
                af[t][c]  = *(const bf16x8*)(&As[(wr + t * 16 + l15) * BK + c * 32 + quad * 8]);
                bfr[t][c] = *(const bf16x8*)(&Bs[(wc + t * 16 + l15) * BK + c * 32 + quad * 8]);
            }
#pragma unroll
        for (int c = 0; c < 2; c++)
#pragma unroll
            for (int mt = 0; mt < 4; mt++)
#pragma unroll
                for (int nt = 0; nt < 4; nt++)
                    acc[mt][nt] = __builtin_amdgcn_mfma_f32_16x16x32_bf16(
                        af[mt][c], bfr[nt][c], acc[mt][nt], 0, 0, 0);
    }

#pragma unroll
    for (int mt = 0; mt < 4; mt++)
#pragma unroll
        for (int nt = 0; nt < 4; nt++)
#pragma unroll
            for (int r = 0; r < 4; r++) {
                int m = m0 + wr + mt * 16 + quad * 4 + r;
                int n = n0 + wc + nt * 16 + l15;
                cstore(&C[(size_t)m * N + n], acc[mt][nt][r]);
            }
}

// ------- Flash attention: async-LDS-staged K and V^T, static-max softcap ----
#define PS_STRIDE 88  // 64 + 24 pad

__global__ __launch_bounds__(256) void flash_attn(
        const unsigned short* __restrict__ Q,
        const unsigned short* __restrict__ K,
        const unsigned short* __restrict__ Vt,   // [D_MODEL][NB*S_LEN]  (= V^T)
        const float* __restrict__ bias,
        const int* __restrict__ softcap,
        unsigned short* __restrict__ O) {
    __shared__ __align__(16) unsigned short Ks[64 * DK];    // [key][d]  16 KB
    __shared__ __align__(16) unsigned short Vts[DK * 64];   // [d][key]  16 KB
    __shared__ __align__(16) unsigned short Ps[4 * 16 * PS_STRIDE];  // 11 KB

    const int tid = threadIdx.x;
    const int lane = tid & 63;
    const int wave = tid >> 6;
    const int quad = lane >> 4;
    const int l15 = lane & 15;
    const int q0 = blockIdx.x * 64;
    const int h = blockIdx.y;
    const int b = blockIdx.z;

    const float scale = 0.08838834764831845f;  // 1/sqrt(128)
    const float cap = (float)softcap[0];
    const float LOG2E = 1.4426950408889634f;
    const float c1 = 2.0f * LOG2E * scale / cap;
    const float c2 = 2.0f * LOG2E / cap;
    const float c3 = -2.0f * cap * LOG2E;

    const size_t head_off = (size_t)b * S_LEN * D_MODEL + (size_t)h * DK;
    const size_t vt_row = (size_t)NB * S_LEN;
    const unsigned short* Vh = Vt + (size_t)h * DK * vt_row + (size_t)b * S_LEN;

    // Q fragments (A-layout): 16 q-rows per wave
    bf16x8 qf[4];
    {
        const unsigned short* Qp = Q + head_off + (size_t)(q0 + wave * 16 + l15) * D_MODEL;
#pragma unroll
        for (int c = 0; c < 4; c++)
            qf[c] = *(const bf16x8*)(Qp + c * 32 + quad * 8);
    }

    f32x4 zero = {0.f, 0.f, 0.f, 0.f};
    float l_part[4] = {0.f, 0.f, 0.f, 0.f};
    f32x4 o_acc[8];
#pragma unroll
    for (int d = 0; d < 8; d++) o_acc[d] = zero;

    unsigned short* Psw = &Ps[wave * 16 * PS_STRIDE];
    const int qrow = q0 + wave * 16 + quad * 4;

    // staging maps (wave-uniform LDS base + lane*16B, as global_load_lds needs)
    // K tile [64][128]: chunk idx = t*256 + tid ; row = idx>>4, col = (idx&15)*8
    const int krow = (wave * 64 + lane) >> 4;          // +t*16 per round
    const int kcol = ((wave * 64 + lane) & 15) * 8;
    // Vt tile [128][64]: row = idx>>3, col = (idx&7)*8
    const int vrow = (wave * 64 + lane) >> 3;          // +t*32 per round
    const int vcol = ((wave * 64 + lane) & 7) * 8;

    for (int kt = 0; kt < S_LEN / 64; kt++) {
        const int kbase = kt * 64;
        __syncthreads();
#pragma unroll
        for (int t = 0; t < 4; t++) {
            gld_lds16(K + head_off + (size_t)(kbase + krow + t * 16) * D_MODEL + kcol,
                      &Ks[(krow + t * 16) * DK + kcol]);
            gld_lds16(Vh + (size_t)(vrow + t * 32) * vt_row + kbase + vcol,
                      &Vts[(vrow + t * 32) * 64 + vcol]);
        }
        __syncthreads();

        // ---- S = Q K^T (16x64 per wave) -----------------------------------
        f32x4 s[4];
#pragma unroll
        for (int nt = 0; nt < 4; nt++) s[nt] = zero;
#pragma unroll
        for (int c = 0; c < 4; c++) {
            bf16x8 kf[4];
#pragma unroll
            for (int nt = 0; nt < 4; nt++)
                kf[nt] = *(const bf16x8*)(&Ks[(nt * 16 + l15) * DK + c * 32 + quad * 8]);
#pragma unroll
            for (int nt = 0; nt < 4; nt++)
                s[nt] = __builtin_amdgcn_mfma_f32_16x16x32_bf16(qf[c], kf[nt], s[nt], 0, 0, 0);
        }

        // ---- fused softcap+softmax (static max = cap) ---------------------
#pragma unroll
        for (int nt = 0; nt < 4; nt++) {
            const float* bp = bias + (size_t)qrow * S_LEN + kbase + nt * 16 + l15;
#pragma unroll
            for (int r = 0; r < 4; r++) {
                float arg = fmaf(s[nt][r], c1, bp[(size_t)r * S_LEN] * c2);
                float u = __builtin_amdgcn_exp2f(arg);
                float p = __builtin_amdgcn_exp2f(c3 * __builtin_amdgcn_rcpf(u + 1.0f));
                s[nt][r] = p;
                l_part[r] += p;
            }
        }

        // ---- P: C-layout -> per-wave LDS -> A-layout ----------------------
#pragma unroll
        for (int nt = 0; nt < 4; nt++)
#pragma unroll
            for (int r = 0; r < 4; r++)
                Psw[(quad * 4 + r) * PS_STRIDE + nt * 16 + l15] = f2bf(s[nt][r]);

        // ---- O += P V  (V^T fragments from LDS) ---------------------------
#pragma unroll
        for (int c = 0; c < 2; c++) {
            bf16x8 pf = *(const bf16x8*)(&Psw[l15 * PS_STRIDE + c * 32 + quad * 8]);
#pragma unroll
            for (int dt = 0; dt < 8; dt++) {
                bf16x8 vf = *(const bf16x8*)(&Vts[(dt * 16 + l15) * 64 + c * 32 + quad * 8]);
                o_acc[dt] = __builtin_amdgcn_mfma_f32_16x16x32_bf16(pf, vf, o_acc[dt], 0, 0, 0);
            }
        }
    }

    // ---- finalize ---------------------------------------------------------
#pragma unroll
    for (int r = 0; r < 4; r++) {
        float l = l_part[r];
        l += __shfl_xor(l, 1, 64);
        l += __shfl_xor(l, 2, 64);
        l += __shfl_xor(l, 4, 64);
        l += __shfl_xor(l, 8, 64);
        float inv = 1.0f / l;
        int row = qrow + r;
        unsigned short* Op = O + (size_t)(b * S_LEN + row) * D_MODEL + h * DK;
#pragma unroll
        for (int dt = 0; dt < 8; dt++)
            Op[dt * 16 + l15] = f2bf(o_acc[dt][r] * inv);
    }
}

// ---------------- host ----------------
extern "C" void kernel_launch(void* const* d_in, const int* in_sizes, int n_in,
                              void* d_out, int out_size, void* d_ws, size_t ws_size,
                              hipStream_t stream) {
    const float* inp = (const float*)d_in[0];
    const float* wq  = (const float*)d_in[1];
    const float* wk  = (const float*)d_in[2];
    const float* wv  = (const float*)d_in[3];
    const float* wo  = (const float*)d_in[4];
    const float* bias = (const float*)d_in[5];
    const int* softcap = (const int*)d_in[6];
    float* out = (float*)d_out;

    unsigned short* ws = (unsigned short*)d_ws;
    const size_t n_inp = (size_t)NB * S_LEN * D_MODEL;
    const size_t n_w = (size_t)D_MODEL * D_MODEL;
    unsigned short* inp_b = ws;
    unsigned short* wq_b = inp_b + n_inp;
    unsigned short* wk_b = wq_b + n_w;
    unsigned short* wv_b = wk_b + n_w;
    unsigned short* wo_b = wv_b + n_w;
    unsigned short* Qb = wo_b + n_w;
    unsigned short* Kb = Qb + n_inp;
    unsigned short* Vtb = Kb + n_inp;   // [D_MODEL][NB*S_LEN] = V^T
    unsigned short* Ob = Vtb + n_inp;

    cast_f32_to_bf16<<<dim3(1024), dim3(256), 0, stream>>>(inp, inp_b, (int)(n_inp / 4));
    cast_f32_to_bf16<<<dim3(512), dim3(256), 0, stream>>>(wq, wq_b, (int)(n_w / 4));
    cast_f32_to_bf16<<<dim3(512), dim3(256), 0, stream>>>(wk, wk_b, (int)(n_w / 4));
    cast_f32_to_bf16<<<dim3(512), dim3(256), 0, stream>>>(wv, wv_b, (int)(n_w / 4));
    cast_f32_to_bf16<<<dim3(512), dim3(256), 0, stream>>>(wo, wo_b, (int)(n_w / 4));

    dim3 gg(NB * S_LEN / BM, D_MODEL / BN);  // (32, 16)
    gemm_bt<unsigned short><<<gg, 256, 0, stream>>>(inp_b, wq_b, Qb, NB * S_LEN, D_MODEL, D_MODEL);
    gemm_bt<unsigned short><<<gg, 256, 0, stream>>>(inp_b, wk_b, Kb, NB * S_LEN, D_MODEL, D_MODEL);
    dim3 gv(D_MODEL / BM, NB * S_LEN / BN);  // (16, 32)
    gemm_bt<unsigned short><<<gv, 256, 0, stream>>>(wv_b, inp_b, Vtb, D_MODEL, NB * S_LEN, D_MODEL);

    flash_attn<<<dim3(S_LEN / 64, NH, NB), 256, 0, stream>>>(Qb, Kb, Vtb, bias, softcap, Ob);

    gemm_bt<float><<<gg, 256, 0, stream>>>(Ob, wo_b, out, NB * S_LEN, D_MODEL, D_MODEL);
}

// Round 4
// 545.504 us; speedup vs baseline: 1.6697x; 1.2978x over previous
//
#include <hip/hip_runtime.h>

#define D_MODEL 2048
#define S_LEN 2048
#define NB 2
#define NH 16
#define DK 128

typedef __attribute__((ext_vector_type(8))) __bf16 bf16x8;
typedef __attribute__((ext_vector_type(4))) float f32x4;

__device__ __forceinline__ unsigned short f2bf(float f) {
    unsigned int u = __float_as_uint(f);
    return (unsigned short)((u + 0x7fffu + ((u >> 16) & 1u)) >> 16);
}

__device__ __forceinline__ void gld_lds16(const void* g, void* l) {
    __builtin_amdgcn_global_load_lds(
        (const __attribute__((address_space(1))) unsigned int*)g,
        (__attribute__((address_space(3))) unsigned int*)l, 16, 0, 0);
}

__global__ void cast_f32_to_bf16(const float* __restrict__ x,
                                 unsigned short* __restrict__ y, int n4) {
    int i = blockIdx.x * blockDim.x + threadIdx.x;
    int stride = gridDim.x * blockDim.x;
    const float4* x4 = (const float4*)x;
    ushort4* y4 = (ushort4*)y;
    for (; i < n4; i += stride) {
        float4 v = x4[i];
        ushort4 o;
        o.x = f2bf(v.x); o.y = f2bf(v.y); o.z = f2bf(v.z); o.w = f2bf(v.w);
        y4[i] = o;
    }
}

// -------- GEMM (m97 + XOR-swizzled LDS): C[m,n] = sum_k A[m,k]*Bt[n,k] ------
#define BM 128
#define BN 128
#define BK 64
// LDS layout: row r (BK=64 u16 = 8 chunks of 16B), chunk c stored at c^(r&7).

__device__ __forceinline__ void cstore(float* p, float v) { *p = v; }
__device__ __forceinline__ void cstore(unsigned short* p, float v) { *p = f2bf(v); }

template <typename OutT>
__global__ __launch_bounds__(256) void gemm_bt(const unsigned short* __restrict__ A,
                                               const unsigned short* __restrict__ Bt,
                                               OutT* __restrict__ C,
                                               int M, int N, int K) {
    __shared__ __align__(16) unsigned short As[BM * BK];
    __shared__ __align__(16) unsigned short Bs[BN * BK];
    const int tid = threadIdx.x;
    const int lane = tid & 63;
    const int wave = tid >> 6;
    const int quad = lane >> 4;
    const int l15 = lane & 15;
    const int wr = (wave >> 1) * 64;
    const int wc = (wave & 1) * 64;
    const int m0 = blockIdx.x * BM;
    const int n0 = blockIdx.y * BN;

    const int slotbase = wave * 64 + lane;

    f32x4 zero = {0.f, 0.f, 0.f, 0.f};
    f32x4 acc[4][4];
    for (int i = 0; i < 4; i++)
        for (int j = 0; j < 4; j++) acc[i][j] = zero;

    for (int k0 = 0; k0 < K; k0 += BK) {
        __syncthreads();
#pragma unroll
        for (int t = 0; t < 4; t++) {
            int slot = t * 256 + slotbase;
            int row = slot >> 3;
            int cg = (slot & 7) ^ (row & 7);   // global chunk for this slot
            gld_lds16(A + (size_t)(m0 + row) * K + k0 + cg * 8, &As[slot * 8]);
            gld_lds16(Bt + (size_t)(n0 + row) * K + k0 + cg * 8, &Bs[slot * 8]);
        }
        __syncthreads();

        bf16x8 af[4][2], bfr[4][2];
#pragma unroll
        for (int t = 0; t < 4; t++)
#pragma unroll
            for (int c = 0; c < 2; c++) {
                int ch = (c * 4 + quad) ^ (l15 & 7);
                af[t][c]  = *(const bf16x8*)(&As[((wr + t * 16 + l15) * 8 + ch) * 8]);
                bfr[t][c] = *(const bf16x8*)(&Bs[((wc + t * 16 + l15) * 8 + ch) * 8]);
            }
#pragma unroll
        for (int c = 0; c < 2; c++)
#pragma unroll
            for (int mt = 0; mt < 4; mt++)
#pragma unroll
                for (int nt = 0; nt < 4; nt++)
                    acc[mt][nt] = __builtin_amdgcn_mfma_f32_16x16x32_bf16(
                        af[mt][c], bfr[nt][c], acc[mt][nt], 0, 0, 0);
    }

#pragma unroll
    for (int mt = 0; mt < 4; mt++)
#pragma unroll
        for (int nt = 0; nt < 4; nt++)
#pragma unroll
            for (int r = 0; r < 4; r++) {
                int m = m0 + wr + mt * 16 + quad * 4 + r;
                int n = n0 + wc + nt * 16 + l15;
                cstore(&C[(size_t)m * N + n], acc[mt][nt][r]);
            }
}

// ---- Flash attention: swizzled LDS, 128 q-rows/block, static-max softcap ---
#define QT 128
#define PS_STRIDE 72  // 64 + 8 pad (stride 36 dw ≡ 4 mod 32 → 2-way max)

__global__ __launch_bounds__(256) void flash_attn(
        const unsigned short* __restrict__ Q,
        const unsigned short* __restrict__ K,
        const unsigned short* __restrict__ Vt,   // [D_MODEL][NB*S_LEN]  (= V^T)
        const float* __restrict__ bias,
        const int* __restrict__ softcap,
        unsigned short* __restrict__ O) {
    // K tile [64 r][16 ch], chunk c at c^(r&15); V^T tile [128 r][8 ch], c^(r&7)
    __shared__ __align__(16) unsigned short Ks[64 * DK];     // 16 KB
    __shared__ __align__(16) unsigned short Vts[DK * 64];    // 16 KB
    __shared__ __align__(16) unsigned short Ps[4 * 32 * PS_STRIDE];  // 18 KB

    const int tid = threadIdx.x;
    const int lane = tid & 63;
    const int wave = tid >> 6;
    const int quad = lane >> 4;
    const int l15 = lane & 15;
    const int q0 = blockIdx.x * QT;
    const int h = blockIdx.y;
    const int b = blockIdx.z;

    const float scale = 0.08838834764831845f;  // 1/sqrt(128)
    const float cap = (float)softcap[0];
    const float LOG2E = 1.4426950408889634f;
    const float c1 = 2.0f * LOG2E * scale / cap;
    const float c2 = 2.0f * LOG2E / cap;
    const float c3 = -2.0f * cap * LOG2E;

    const size_t head_off = (size_t)b * S_LEN * D_MODEL + (size_t)h * DK;
    const size_t vt_row = (size_t)NB * S_LEN;
    const unsigned short* Vh = Vt + (size_t)h * DK * vt_row + (size_t)b * S_LEN;

    // Q fragments (A-layout): 2 sub-tiles of 16 q-rows per wave
    bf16x8 qf[2][4];
#pragma unroll
    for (int qs = 0; qs < 2; qs++) {
        const unsigned short* Qp = Q + head_off +
            (size_t)(q0 + wave * 32 + qs * 16 + l15) * D_MODEL;
#pragma unroll
        for (int c = 0; c < 4; c++)
            qf[qs][c] = *(const bf16x8*)(Qp + c * 32 + quad * 8);
    }

    f32x4 zero = {0.f, 0.f, 0.f, 0.f};
    float l_part[2][4] = {{0.f, 0.f, 0.f, 0.f}, {0.f, 0.f, 0.f, 0.f}};
    f32x4 o_acc[2][8];
#pragma unroll
    for (int qs = 0; qs < 2; qs++)
#pragma unroll
        for (int d = 0; d < 8; d++) o_acc[qs][d] = zero;

    unsigned short* Psw = &Ps[wave * 32 * PS_STRIDE];
    const int slotbase = wave * 64 + lane;

    for (int kt = 0; kt < S_LEN / 64; kt++) {
        const int kbase = kt * 64;
        __syncthreads();
#pragma unroll
        for (int t = 0; t < 4; t++) {
            int slot = t * 256 + slotbase;
            int kr = slot >> 4;
            int kc = (slot & 15) ^ (kr & 15);
            gld_lds16(K + head_off + (size_t)(kbase + kr) * D_MODEL + kc * 8,
                      &Ks[slot * 8]);
            int vr = slot >> 3;
            int vc = (slot & 7) ^ (vr & 7);
            gld_lds16(Vh + (size_t)vr * vt_row + kbase + vc * 8,
                      &Vts[slot * 8]);
        }
        __syncthreads();

        // ---- S = Q K^T : kf shared across both q sub-tiles ----------------
        f32x4 s[2][4];
#pragma unroll
        for (int qs = 0; qs < 2; qs++)
#pragma unroll
            for (int nt = 0; nt < 4; nt++) s[qs][nt] = zero;
#pragma unroll
        for (int c = 0; c < 4; c++) {
            bf16x8 kf[4];
#pragma unroll
            for (int nt = 0; nt < 4; nt++)
                kf[nt] = *(const bf16x8*)(&Ks[((nt * 16 + l15) * 16 +
                                               ((c * 4 + quad) ^ l15)) * 8]);
#pragma unroll
            for (int nt = 0; nt < 4; nt++)
#pragma unroll
                for (int qs = 0; qs < 2; qs++)
                    s[qs][nt] = __builtin_amdgcn_mfma_f32_16x16x32_bf16(
                        qf[qs][c], kf[nt], s[qs][nt], 0, 0, 0);
        }

        // ---- fused softcap+softmax (static max = cap) ---------------------
#pragma unroll
        for (int qs = 0; qs < 2; qs++) {
            const int qrow = q0 + wave * 32 + qs * 16 + quad * 4;
#pragma unroll
            for (int nt = 0; nt < 4; nt++) {
                const float* bp = bias + (size_t)qrow * S_LEN + kbase + nt * 16 + l15;
#pragma unroll
                for (int r = 0; r < 4; r++) {
                    float arg = fmaf(s[qs][nt][r], c1, bp[(size_t)r * S_LEN] * c2);
                    float u = __builtin_amdgcn_exp2f(arg);
                    float p = __builtin_amdgcn_exp2f(c3 * __builtin_amdgcn_rcpf(u + 1.0f));
                    s[qs][nt][r] = p;
                    l_part[qs][r] += p;
                }
            }
        }

        // ---- P: C-layout -> per-wave LDS -> A-layout ----------------------
#pragma unroll
        for (int qs = 0; qs < 2; qs++)
#pragma unroll
            for (int nt = 0; nt < 4; nt++)
#pragma unroll
                for (int r = 0; r < 4; r++)
                    Psw[(qs * 16 + quad * 4 + r) * PS_STRIDE + nt * 16 + l15] =
                        f2bf(s[qs][nt][r]);

        // ---- O += P V : vf shared across both q sub-tiles -----------------
#pragma unroll
        for (int c = 0; c < 2; c++) {
            bf16x8 pf[2];
#pragma unroll
            for (int qs = 0; qs < 2; qs++)
                pf[qs] = *(const bf16x8*)(&Psw[(qs * 16 + l15) * PS_STRIDE +
                                               c * 32 + quad * 8]);
#pragma unroll
            for (int dt = 0; dt < 8; dt++) {
                bf16x8 vf = *(const bf16x8*)(&Vts[((dt * 16 + l15) * 8 +
                                                   ((c * 4 + quad) ^ (l15 & 7))) * 8]);
#pragma unroll
                for (int qs = 0; qs < 2; qs++)
                    o_acc[qs][dt] = __builtin_amdgcn_mfma_f32_16x16x32_bf16(
                        pf[qs], vf, o_acc[qs][dt], 0, 0, 0);
            }
        }
    }

    // ---- finalize ---------------------------------------------------------
#pragma unroll
    for (int qs = 0; qs < 2; qs++)
#pragma unroll
        for (int r = 0; r < 4; r++) {
            float l = l_part[qs][r];
            l += __shfl_xor(l, 1, 64);
            l += __shfl_xor(l, 2, 64);
            l += __shfl_xor(l, 4, 64);
            l += __shfl_xor(l, 8, 64);
            float inv = 1.0f / l;
            int row = q0 + wave * 32 + qs * 16 + quad * 4 + r;
            unsigned short* Op = O + (size_t)(b * S_LEN + row) * D_MODEL + h * DK;
#pragma unroll
            for (int dt = 0; dt < 8; dt++)
                Op[dt * 16 + l15] = f2bf(o_acc[qs][dt][r] * inv);
        }
}

// ---------------- host ----------------
extern "C" void kernel_launch(void* const* d_in, const int* in_sizes, int n_in,
                              void* d_out, int out_size, void* d_ws, size_t ws_size,
                              hipStream_t stream) {
    const float* inp = (const float*)d_in[0];
    const float* wq  = (const float*)d_in[1];
    const float* wk  = (const float*)d_in[2];
    const float* wv  = (const float*)d_in[3];
    const float* wo  = (const float*)d_in[4];
    const float* bias = (const float*)d_in[5];
    const int* softcap = (const int*)d_in[6];
    float* out = (float*)d_out;

    unsigned short* ws = (unsigned short*)d_ws;
    const size_t n_inp = (size_t)NB * S_LEN * D_MODEL;
    const size_t n_w = (size_t)D_MODEL * D_MODEL;
    unsigned short* inp_b = ws;
    unsigned short* wq_b = inp_b + n_inp;
    unsigned short* wk_b = wq_b + n_w;
    unsigned short* wv_b = wk_b + n_w;
    unsigned short* wo_b = wv_b + n_w;
    unsigned short* Qb = wo_b + n_w;
    unsigned short* Kb = Qb + n_inp;
    unsigned short* Vtb = Kb + n_inp;   // [D_MODEL][NB*S_LEN] = V^T
    unsigned short* Ob = Vtb + n_inp;

    cast_f32_to_bf16<<<dim3(1024), dim3(256), 0, stream>>>(inp, inp_b, (int)(n_inp / 4));
    cast_f32_to_bf16<<<dim3(512), dim3(256), 0, stream>>>(wq, wq_b, (int)(n_w / 4));
    cast_f32_to_bf16<<<dim3(512), dim3(256), 0, stream>>>(wk, wk_b, (int)(n_w / 4));
    cast_f32_to_bf16<<<dim3(512), dim3(256), 0, stream>>>(wv, wv_b, (int)(n_w / 4));
    cast_f32_to_bf16<<<dim3(512), dim3(256), 0, stream>>>(wo, wo_b, (int)(n_w / 4));

    dim3 gg(NB * S_LEN / BM, D_MODEL / BN);  // (32, 16)
    gemm_bt<unsigned short><<<gg, 256, 0, stream>>>(inp_b, wq_b, Qb, NB * S_LEN, D_MODEL, D_MODEL);
    gemm_bt<unsigned short><<<gg, 256, 0, stream>>>(inp_b, wk_b, Kb, NB * S_LEN, D_MODEL, D_MODEL);
    dim3 gv(D_MODEL / BM, NB * S_LEN / BN);  // (16, 32)
    gemm_bt<unsigned short><<<gv, 256, 0, stream>>>(wv_b, inp_b, Vtb, D_MODEL, NB * S_LEN, D_MODEL);

    flash_attn<<<dim3(S_LEN / QT, NH, NB), 256, 0, stream>>>(Qb, Kb, Vtb, bias, softcap, Ob);

    gemm_bt<float><<<gg, 256, 0, stream>>>(Ob, wo_b, out, NB * S_LEN, D_MODEL, D_MODEL);
}

// Round 5
// 449.535 us; speedup vs baseline: 2.0262x; 1.2135x over previous
//
#include <hip/hip_runtime.h>

#define D_MODEL 2048
#define S_LEN 2048
#define NB 2
#define NH 16
#define DK 128

typedef __attribute__((ext_vector_type(8))) __bf16 bf16x8;
typedef __attribute__((ext_vector_type(4))) float f32x4;

__device__ __forceinline__ unsigned short f2bf(float f) {
    union { __bf16 b; unsigned short u; } cv;
    cv.b = (__bf16)f;   // hardware v_cvt, RNE
    return cv.u;
}

__device__ __forceinline__ void gld_lds16(const void* g, void* l) {
    __builtin_amdgcn_global_load_lds(
        (const __attribute__((address_space(1))) unsigned int*)g,
        (__attribute__((address_space(3))) unsigned int*)l, 16, 0, 0);
}

__global__ void cast_f32_to_bf16(const float* __restrict__ x,
                                 unsigned short* __restrict__ y, int n4) {
    int i = blockIdx.x * blockDim.x + threadIdx.x;
    int stride = gridDim.x * blockDim.x;
    const float4* x4 = (const float4*)x;
    ushort4* y4 = (ushort4*)y;
    for (; i < n4; i += stride) {
        float4 v = x4[i];
        ushort4 o;
        o.x = f2bf(v.x); o.y = f2bf(v.y); o.z = f2bf(v.z); o.w = f2bf(v.w);
        y4[i] = o;
    }
}

// one launch for the 4 equal-size weight matrices
__global__ void cast4_f32_to_bf16(const float* __restrict__ x0, const float* __restrict__ x1,
                                  const float* __restrict__ x2, const float* __restrict__ x3,
                                  unsigned short* y0, unsigned short* y1,
                                  unsigned short* y2, unsigned short* y3, int n4) {
    const float* x = (blockIdx.y == 0) ? x0 : (blockIdx.y == 1) ? x1 : (blockIdx.y == 2) ? x2 : x3;
    unsigned short* y = (blockIdx.y == 0) ? y0 : (blockIdx.y == 1) ? y1 : (blockIdx.y == 2) ? y2 : y3;
    int i = blockIdx.x * blockDim.x + threadIdx.x;
    int stride = gridDim.x * blockDim.x;
    const float4* x4 = (const float4*)x;
    ushort4* y4 = (ushort4*)y;
    for (; i < n4; i += stride) {
        float4 v = x4[i];
        ushort4 o;
        o.x = f2bf(v.x); o.y = f2bf(v.y); o.z = f2bf(v.z); o.w = f2bf(v.w);
        y4[i] = o;
    }
}

// -------- GEMM (m97 + XOR-swizzled LDS): C[m,n] = sum_k A[m,k]*Bt[n,k] ------
#define BM 128
#define BN 128
#define BK 64

__device__ __forceinline__ void cstore(float* p, float v) { *p = v; }
__device__ __forceinline__ void cstore(unsigned short* p, float v) { *p = f2bf(v); }

template <typename OutT>
__global__ __launch_bounds__(256) void gemm_bt(const unsigned short* __restrict__ A,
                                               const unsigned short* __restrict__ Bt,
                                               OutT* __restrict__ C,
                                               int M, int N, int K) {
    __shared__ __align__(16) unsigned short As[BM * BK];
    __shared__ __align__(16) unsigned short Bs[BN * BK];
    const int tid = threadIdx.x;
    const int lane = tid & 63;
    const int wave = tid >> 6;
    const int quad = lane >> 4;
    const int l15 = lane & 15;
    const int wr = (wave >> 1) * 64;
    const int wc = (wave & 1) * 64;
    const int m0 = blockIdx.x * BM;
    const int n0 = blockIdx.y * BN;

    const int slotbase = wave * 64 + lane;

    f32x4 zero = {0.f, 0.f, 0.f, 0.f};
    f32x4 acc[4][4];
    for (int i = 0; i < 4; i++)
        for (int j = 0; j < 4; j++) acc[i][j] = zero;

    for (int k0 = 0; k0 < K; k0 += BK) {
        __syncthreads();
#pragma unroll
        for (int t = 0; t < 4; t++) {
            int slot = t * 256 + slotbase;
            int row = slot >> 3;
            int cg = (slot & 7) ^ (row & 7);
            gld_lds16(A + (size_t)(m0 + row) * K + k0 + cg * 8, &As[slot * 8]);
            gld_lds16(Bt + (size_t)(n0 + row) * K + k0 + cg * 8, &Bs[slot * 8]);
        }
        __syncthreads();

        bf16x8 af[4][2], bfr[4][2];
#pragma unroll
        for (int t = 0; t < 4; t++)
#pragma unroll
            for (int c = 0; c < 2; c++) {
                int ch = (c * 4 + quad) ^ (l15 & 7);
                af[t][c]  = *(const bf16x8*)(&As[((wr + t * 16 + l15) * 8 + ch) * 8]);
                bfr[t][c] = *(const bf16x8*)(&Bs[((wc + t * 16 + l15) * 8 + ch) * 8]);
            }
#pragma unroll
        for (int c = 0; c < 2; c++)
#pragma unroll
            for (int mt = 0; mt < 4; mt++)
#pragma unroll
                for (int nt = 0; nt < 4; nt++)
                    acc[mt][nt] = __builtin_amdgcn_mfma_f32_16x16x32_bf16(
                        af[mt][c], bfr[nt][c], acc[mt][nt], 0, 0, 0);
    }

#pragma unroll
    for (int mt = 0; mt < 4; mt++)
#pragma unroll
        for (int nt = 0; nt < 4; nt++)
#pragma unroll
            for (int r = 0; r < 4; r++) {
                int m = m0 + wr + mt * 16 + quad * 4 + r;
                int n = n0 + wc + nt * 16 + l15;
                cstore(&C[(size_t)m * N + n], acc[mt][nt][r]);
            }
}

// ---- Flash attention: 512 thr / 8 waves, QT=128, swizzled LDS --------------
#define QT 128
#define PS_STRIDE 72  // 64 + 8 pad

__global__ __launch_bounds__(512, 4) void flash_attn(
        const unsigned short* __restrict__ Q,
        const unsigned short* __restrict__ K,
        const unsigned short* __restrict__ Vt,   // [D_MODEL][NB*S_LEN]  (= V^T)
        const float* __restrict__ bias,
        const int* __restrict__ softcap,
        unsigned short* __restrict__ O) {
    // K tile [64 r][16 ch], chunk c at c^(r&15); V^T tile [128 r][8 ch], c^(r&7)
    __shared__ __align__(16) unsigned short Ks[64 * DK];     // 16 KB
    __shared__ __align__(16) unsigned short Vts[DK * 64];    // 16 KB
    __shared__ __align__(16) unsigned short Ps[8 * 16 * PS_STRIDE];  // 18 KB

    const int tid = threadIdx.x;
    const int lane = tid & 63;
    const int wave = tid >> 6;          // 0..7
    const int quad = lane >> 4;
    const int l15 = lane & 15;
    const int q0 = blockIdx.x * QT;
    const int h = blockIdx.y;
    const int b = blockIdx.z;

    const float scale = 0.08838834764831845f;  // 1/sqrt(128)
    const float cap = (float)softcap[0];
    const float LOG2E = 1.4426950408889634f;
    const float c1 = 2.0f * LOG2E * scale / cap;
    const float c2 = 2.0f * LOG2E / cap;
    const float c3 = -2.0f * cap * LOG2E;

    const size_t head_off = (size_t)b * S_LEN * D_MODEL + (size_t)h * DK;
    const size_t vt_row = (size_t)NB * S_LEN;
    const unsigned short* Vh = Vt + (size_t)h * DK * vt_row + (size_t)b * S_LEN;

    // Q fragments (A-layout): 16 q-rows per wave
    bf16x8 qf[4];
    {
        const unsigned short* Qp = Q + head_off + (size_t)(q0 + wave * 16 + l15) * D_MODEL;
#pragma unroll
        for (int c = 0; c < 4; c++)
            qf[c] = *(const bf16x8*)(Qp + c * 32 + quad * 8);
    }

    f32x4 zero = {0.f, 0.f, 0.f, 0.f};
    float l_part[4] = {0.f, 0.f, 0.f, 0.f};
    f32x4 o_acc[8];
#pragma unroll
    for (int d = 0; d < 8; d++) o_acc[d] = zero;

    unsigned short* Psw = &Ps[wave * 16 * PS_STRIDE];
    const int qrow = q0 + wave * 16 + quad * 4;

    for (int kt = 0; kt < S_LEN / 64; kt++) {
        const int kbase = kt * 64;
        __syncthreads();
        // stage 32 KB with 512 lanes x 2 chunks each for K and V^T
#pragma unroll
        for (int t = 0; t < 2; t++) {
            int slot = t * 512 + tid;               // 0..1023
            int kr = slot >> 4;
            int kc = (slot & 15) ^ (kr & 15);
            gld_lds16(K + head_off + (size_t)(kbase + kr) * D_MODEL + kc * 8,
                      &Ks[slot * 8]);
            int vr = slot >> 3;
            int vc = (slot & 7) ^ (vr & 7);
            gld_lds16(Vh + (size_t)vr * vt_row + kbase + vc * 8,
                      &Vts[slot * 8]);
        }
        __syncthreads();

        // ---- S = Q K^T (16 q-rows x 64 keys per wave) ---------------------
        f32x4 s[4];
#pragma unroll
        for (int nt = 0; nt < 4; nt++) s[nt] = zero;
#pragma unroll
        for (int c = 0; c < 4; c++) {
            bf16x8 kf[4];
#pragma unroll
            for (int nt = 0; nt < 4; nt++)
                kf[nt] = *(const bf16x8*)(&Ks[((nt * 16 + l15) * 16 +
                                               ((c * 4 + quad) ^ l15)) * 8]);
#pragma unroll
            for (int nt = 0; nt < 4; nt++)
                s[nt] = __builtin_amdgcn_mfma_f32_16x16x32_bf16(qf[c], kf[nt], s[nt], 0, 0, 0);
        }

        // ---- fused softcap+softmax (static max = cap) ---------------------
#pragma unroll
        for (int nt = 0; nt < 4; nt++) {
            const float* bp = bias + (size_t)qrow * S_LEN + kbase + nt * 16 + l15;
#pragma unroll
            for (int r = 0; r < 4; r++) {
                float arg = fmaf(s[nt][r], c1, bp[(size_t)r * S_LEN] * c2);
                float u = __builtin_amdgcn_exp2f(arg);
                float p = __builtin_amdgcn_exp2f(c3 * __builtin_amdgcn_rcpf(u + 1.0f));
                s[nt][r] = p;
                l_part[r] += p;
            }
        }

        // ---- P: C-layout -> per-wave LDS -> A-layout (no barrier) ---------
#pragma unroll
        for (int nt = 0; nt < 4; nt++)
#pragma unroll
            for (int r = 0; r < 4; r++)
                Psw[(quad * 4 + r) * PS_STRIDE + nt * 16 + l15] = f2bf(s[nt][r]);

        // ---- O += P V -----------------------------------------------------
#pragma unroll
        for (int c = 0; c < 2; c++) {
            bf16x8 pf = *(const bf16x8*)(&Psw[l15 * PS_STRIDE + c * 32 + quad * 8]);
#pragma unroll
            for (int dt = 0; dt < 8; dt++) {
                bf16x8 vf = *(const bf16x8*)(&Vts[((dt * 16 + l15) * 8 +
                                                   ((c * 4 + quad) ^ (l15 & 7))) * 8]);
                o_acc[dt] = __builtin_amdgcn_mfma_f32_16x16x32_bf16(pf, vf, o_acc[dt], 0, 0, 0);
            }
        }
    }

    // ---- finalize ---------------------------------------------------------
#pragma unroll
    for (int r = 0; r < 4; r++) {
        float l = l_part[r];
        l += __shfl_xor(l, 1, 64);
        l += __shfl_xor(l, 2, 64);
        l += __shfl_xor(l, 4, 64);
        l += __shfl_xor(l, 8, 64);
        float inv = 1.0f / l;
        int row = qrow + r;
        unsigned short* Op = O + (size_t)(b * S_LEN + row) * D_MODEL + h * DK;
#pragma unroll
        for (int dt = 0; dt < 8; dt++)
            Op[dt * 16 + l15] = f2bf(o_acc[dt][r] * inv);
    }
}

// ---------------- host ----------------
extern "C" void kernel_launch(void* const* d_in, const int* in_sizes, int n_in,
                              void* d_out, int out_size, void* d_ws, size_t ws_size,
                              hipStream_t stream) {
    const float* inp = (const float*)d_in[0];
    const float* wq  = (const float*)d_in[1];
    const float* wk  = (const float*)d_in[2];
    const float* wv  = (const float*)d_in[3];
    const float* wo  = (const float*)d_in[4];
    const float* bias = (const float*)d_in[5];
    const int* softcap = (const int*)d_in[6];
    float* out = (float*)d_out;

    unsigned short* ws = (unsigned short*)d_ws;
    const size_t n_inp = (size_t)NB * S_LEN * D_MODEL;
    const size_t n_w = (size_t)D_MODEL * D_MODEL;
    unsigned short* inp_b = ws;
    unsigned short* wq_b = inp_b + n_inp;
    unsigned short* wk_b = wq_b + n_w;
    unsigned short* wv_b = wk_b + n_w;
    unsigned short* wo_b = wv_b + n_w;
    unsigned short* Qb = wo_b + n_w;
    unsigned short* Kb = Qb + n_inp;
    unsigned short* Vtb = Kb + n_inp;   // [D_MODEL][NB*S_LEN] = V^T
    unsigned short* Ob = Vtb + n_inp;

    cast_f32_to_bf16<<<dim3(1024), dim3(256), 0, stream>>>(inp, inp_b, (int)(n_inp / 4));
    cast4_f32_to_bf16<<<dim3(256, 4), dim3(256), 0, stream>>>(
        wq, wk, wv, wo, wq_b, wk_b, wv_b, wo_b, (int)(n_w / 4));

    dim3 gg(NB * S_LEN / BM, D_MODEL / BN);  // (32, 16)
    gemm_bt<unsigned short><<<gg, 256, 0, stream>>>(inp_b, wq_b, Qb, NB * S_LEN, D_MODEL, D_MODEL);
    gemm_bt<unsigned short><<<gg, 256, 0, stream>>>(inp_b, wk_b, Kb, NB * S_LEN, D_MODEL, D_MODEL);
    dim3 gv(D_MODEL / BM, NB * S_LEN / BN);  // (16, 32)
    gemm_bt<unsigned short><<<gv, 256, 0, stream>>>(wv_b, inp_b, Vtb, D_MODEL, NB * S_LEN, D_MODEL);

    flash_attn<<<dim3(S_LEN / QT, NH, NB), 512, 0, stream>>>(Qb, Kb, Vtb, bias, softcap, Ob);

    gemm_bt<float><<<gg, 256, 0, stream>>>(Ob, wo_b, out, NB * S_LEN, D_MODEL, D_MODEL);
}

// Round 6
// 438.472 us; speedup vs baseline: 2.0773x; 1.0252x over previous
//
#include <hip/hip_runtime.h>

#define D_MODEL 2048
#define S_LEN 2048
#define NB 2
#define NH 16
#define DK 128

typedef __attribute__((ext_vector_type(8))) __bf16 bf16x8;
typedef __attribute__((ext_vector_type(4))) float f32x4;

__device__ __forceinline__ unsigned short f2bf(float f) {
    union { __bf16 b; unsigned short u; } cv;
    cv.b = (__bf16)f;   // hardware v_cvt, RNE
    return cv.u;
}

__device__ __forceinline__ void gld_lds16(const void* g, void* l) {
    __builtin_amdgcn_global_load_lds(
        (const __attribute__((address_space(1))) unsigned int*)g,
        (__attribute__((address_space(3))) unsigned int*)l, 16, 0, 0);
}

__global__ void cast_f32_to_bf16(const float* __restrict__ x,
                                 unsigned short* __restrict__ y, int n4) {
    int i = blockIdx.x * blockDim.x + threadIdx.x;
    int stride = gridDim.x * blockDim.x;
    const float4* x4 = (const float4*)x;
    ushort4* y4 = (ushort4*)y;
    for (; i < n4; i += stride) {
        float4 v = x4[i];
        ushort4 o;
        o.x = f2bf(v.x); o.y = f2bf(v.y); o.z = f2bf(v.z); o.w = f2bf(v.w);
        y4[i] = o;
    }
}

__global__ void cast4_f32_to_bf16(const float* __restrict__ x0, const float* __restrict__ x1,
                                  const float* __restrict__ x2, const float* __restrict__ x3,
                                  unsigned short* y0, unsigned short* y1,
                                  unsigned short* y2, unsigned short* y3, int n4) {
    const float* x = (blockIdx.y == 0) ? x0 : (blockIdx.y == 1) ? x1 : (blockIdx.y == 2) ? x2 : x3;
    unsigned short* y = (blockIdx.y == 0) ? y0 : (blockIdx.y == 1) ? y1 : (blockIdx.y == 2) ? y2 : y3;
    int i = blockIdx.x * blockDim.x + threadIdx.x;
    int stride = gridDim.x * blockDim.x;
    const float4* x4 = (const float4*)x;
    ushort4* y4 = (ushort4*)y;
    for (; i < n4; i += stride) {
        float4 v = x4[i];
        ushort4 o;
        o.x = f2bf(v.x); o.y = f2bf(v.y); o.z = f2bf(v.z); o.w = f2bf(v.w);
        y4[i] = o;
    }
}

// -------- GEMM (m97 + XOR-swizzled LDS): C[m,n] = sum_k A[m,k]*Bt[n,k] ------
#define BM 128
#define BN 128
#define BK 64

__device__ __forceinline__ void cstore(float* p, float v) { *p = v; }
__device__ __forceinline__ void cstore(unsigned short* p, float v) { *p = f2bf(v); }

template <typename OutT>
__device__ __forceinline__ void gemm_body(const unsigned short* __restrict__ A,
                                          const unsigned short* __restrict__ Bt,
                                          OutT* __restrict__ C,
                                          int M, int N, int K, int m0, int n0) {
    __shared__ __align__(16) unsigned short As[BM * BK];
    __shared__ __align__(16) unsigned short Bs[BN * BK];
    const int tid = threadIdx.x;
    const int lane = tid & 63;
    const int wave = tid >> 6;
    const int quad = lane >> 4;
    const int l15 = lane & 15;
    const int wr = (wave >> 1) * 64;
    const int wc = (wave & 1) * 64;

    const int slotbase = wave * 64 + lane;

    f32x4 zero = {0.f, 0.f, 0.f, 0.f};
    f32x4 acc[4][4];
    for (int i = 0; i < 4; i++)
        for (int j = 0; j < 4; j++) acc[i][j] = zero;

    for (int k0 = 0; k0 < K; k0 += BK) {
        __syncthreads();
#pragma unroll
        for (int t = 0; t < 4; t++) {
            int slot = t * 256 + slotbase;
            int row = slot >> 3;
            int cg = (slot & 7) ^ (row & 7);
            gld_lds16(A + (size_t)(m0 + row) * K + k0 + cg * 8, &As[slot * 8]);
            gld_lds16(Bt + (size_t)(n0 + row) * K + k0 + cg * 8, &Bs[slot * 8]);
        }
        __syncthreads();

        bf16x8 af[4][2], bfr[4][2];
#pragma unroll
        for (int t = 0; t < 4; t++)
#pragma unroll
            for (int c = 0; c < 2; c++) {
                int ch = (c * 4 + quad) ^ (l15 & 7);
                af[t][c]  = *(const bf16x8*)(&As[((wr + t * 16 + l15) * 8 + ch) * 8]);
                bfr[t][c] = *(const bf16x8*)(&Bs[((wc + t * 16 + l15) * 8 + ch) * 8]);
            }
#pragma unroll
        for (int c = 0; c < 2; c++)
#pragma unroll
            for (int mt = 0; mt < 4; mt++)
#pragma unroll
                for (int nt = 0; nt < 4; nt++)
                    acc[mt][nt] = __builtin_amdgcn_mfma_f32_16x16x32_bf16(
                        af[mt][c], bfr[nt][c], acc[mt][nt], 0, 0, 0);
    }

#pragma unroll
    for (int mt = 0; mt < 4; mt++)
#pragma unroll
        for (int nt = 0; nt < 4; nt++)
#pragma unroll
            for (int r = 0; r < 4; r++) {
                int m = m0 + wr + mt * 16 + quad * 4 + r;
                int n = n0 + wc + nt * 16 + l15;
                cstore(&C[(size_t)m * N + n], acc[mt][nt][r]);
            }
}

template <typename OutT>
__global__ __launch_bounds__(256) void gemm_bt(const unsigned short* __restrict__ A,
                                               const unsigned short* __restrict__ Bt,
                                               OutT* __restrict__ C,
                                               int M, int N, int K) {
    gemm_body(A, Bt, C, M, N, K, blockIdx.x * BM, blockIdx.y * BN);
}

// fused Q+K projection: grid (M/BM, 2*N/BN); y<16 -> Q, y>=16 -> K
__global__ __launch_bounds__(256) void gemm_qk(const unsigned short* __restrict__ A,
                                               const unsigned short* __restrict__ Wq,
                                               const unsigned short* __restrict__ Wk,
                                               unsigned short* __restrict__ Qo,
                                               unsigned short* __restrict__ Ko,
                                               int M, int N, int K) {
    const int sel = blockIdx.y >> 4;
    const unsigned short* Bt = sel ? Wk : Wq;
    unsigned short* C = sel ? Ko : Qo;
    gemm_body(A, Bt, C, M, N, K, blockIdx.x * BM, (blockIdx.y & 15) * BN);
}

// ---- Flash attention: 512 thr, QT=128, split-barrier + V double-buffer -----
#define QT 128
#define PS_STRIDE 72  // 64 + 8 pad
#define NT (S_LEN / 64)

__global__ __launch_bounds__(512, 4) void flash_attn(
        const unsigned short* __restrict__ Q,
        const unsigned short* __restrict__ K,
        const unsigned short* __restrict__ Vt,   // [D_MODEL][NB*S_LEN]  (= V^T)
        const float* __restrict__ bias,
        const int* __restrict__ softcap,
        unsigned short* __restrict__ O) {
    // K tile [64 r][16 ch], chunk c at c^(r&15); V^T tile [128 r][8 ch], c^(r&7)
    __shared__ __align__(16) unsigned short Ks[64 * DK];        // 16 KB
    __shared__ __align__(16) unsigned short Vts[2][DK * 64];    // 32 KB (dbuf)
    __shared__ __align__(16) unsigned short Ps[8 * 16 * PS_STRIDE];  // 18 KB

    const int tid = threadIdx.x;
    const int lane = tid & 63;
    const int wave = tid >> 6;          // 0..7
    const int quad = lane >> 4;
    const int l15 = lane & 15;
    const int q0 = blockIdx.x * QT;
    const int h = blockIdx.y;
    const int b = blockIdx.z;

    const float scale = 0.08838834764831845f;  // 1/sqrt(128)
    const float cap = (float)softcap[0];
    const float LOG2E = 1.4426950408889634f;
    const float c1 = 2.0f * LOG2E * scale / cap;
    const float c2 = 2.0f * LOG2E / cap;
    const float c3 = -2.0f * cap * LOG2E;

    const size_t head_off = (size_t)b * S_LEN * D_MODEL + (size_t)h * DK;
    const size_t vt_row = (size_t)NB * S_LEN;
    const unsigned short* Vh = Vt + (size_t)h * DK * vt_row + (size_t)b * S_LEN;

    // Q fragments (A-layout): 16 q-rows per wave
    bf16x8 qf[4];
    {
        const unsigned short* Qp = Q + head_off + (size_t)(q0 + wave * 16 + l15) * D_MODEL;
#pragma unroll
        for (int c = 0; c < 4; c++)
            qf[c] = *(const bf16x8*)(Qp + c * 32 + quad * 8);
    }

    f32x4 zero = {0.f, 0.f, 0.f, 0.f};
    float l_part[4] = {0.f, 0.f, 0.f, 0.f};
    f32x4 o_acc[8];
#pragma unroll
    for (int d = 0; d < 8; d++) o_acc[d] = zero;

    unsigned short* Psw = &Ps[wave * 16 * PS_STRIDE];
    const int qrow = q0 + wave * 16 + quad * 4;

    auto stageK = [&](int kbase) {
#pragma unroll
        for (int t = 0; t < 2; t++) {
            int slot = t * 512 + tid;               // 0..1023
            int kr = slot >> 4;
            int kc = (slot & 15) ^ (kr & 15);
            gld_lds16(K + head_off + (size_t)(kbase + kr) * D_MODEL + kc * 8,
                      &Ks[slot * 8]);
        }
    };
    auto stageV = [&](int kbase, int buf) {
#pragma unroll
        for (int t = 0; t < 2; t++) {
            int slot = t * 512 + tid;
            int vr = slot >> 3;
            int vc = (slot & 7) ^ (vr & 7);
            gld_lds16(Vh + (size_t)vr * vt_row + kbase + vc * 8,
                      &Vts[buf][slot * 8]);
        }
    };

    stageK(0);
    stageV(0, 0);

    for (int kt = 0; kt < NT; kt++) {
        const int kbase = kt * 64;
        __syncthreads();   // A: drains DMA -> Ks=K(kt), Vts[kt&1]=V(kt) ready

        // ---- S = Q K^T (16 q-rows x 64 keys per wave) ---------------------
        f32x4 s[4];
#pragma unroll
        for (int nt = 0; nt < 4; nt++) s[nt] = zero;
#pragma unroll
        for (int c = 0; c < 4; c++) {
            bf16x8 kf[4];
#pragma unroll
            for (int nt = 0; nt < 4; nt++)
                kf[nt] = *(const bf16x8*)(&Ks[((nt * 16 + l15) * 16 +
                                               ((c * 4 + quad) ^ l15)) * 8]);
#pragma unroll
            for (int nt = 0; nt < 4; nt++)
                s[nt] = __builtin_amdgcn_mfma_f32_16x16x32_bf16(qf[c], kf[nt], s[nt], 0, 0, 0);
        }

        __syncthreads();   // B: Ks and Vts[(kt+1)&1] free for restaging

        // bias prefetch BEFORE the DMA issue (in-order vmcnt retirement)
        float bb[4][4];
#pragma unroll
        for (int nt = 0; nt < 4; nt++) {
            const float* bp = bias + (size_t)qrow * S_LEN + kbase + nt * 16 + l15;
#pragma unroll
            for (int r = 0; r < 4; r++)
                bb[nt][r] = bp[(size_t)r * S_LEN];
        }
        __builtin_amdgcn_sched_barrier(0);

        if (kt + 1 < NT) {       // async prefetch next tile; drains at next A
            stageK(kbase + 64);
            stageV(kbase + 64, (kt + 1) & 1);
        }

        // ---- fused softcap+softmax (static max = cap) ---------------------
#pragma unroll
        for (int nt = 0; nt < 4; nt++) {
#pragma unroll
            for (int r = 0; r < 4; r++) {
                float arg = fmaf(s[nt][r], c1, bb[nt][r] * c2);
                float u = __builtin_amdgcn_exp2f(arg);
                float p = __builtin_amdgcn_exp2f(c3 * __builtin_amdgcn_rcpf(u + 1.0f));
                s[nt][r] = p;
                l_part[r] += p;
            }
        }

        // ---- P: C-layout -> per-wave LDS -> A-layout (no barrier) ---------
#pragma unroll
        for (int nt = 0; nt < 4; nt++)
#pragma unroll
            for (int r = 0; r < 4; r++)
                Psw[(quad * 4 + r) * PS_STRIDE + nt * 16 + l15] = f2bf(s[nt][r]);

        // ---- O += P V  (from the completed V buffer) ----------------------
        const unsigned short* Vcur = Vts[kt & 1];
#pragma unroll
        for (int c = 0; c < 2; c++) {
            bf16x8 pf = *(const bf16x8*)(&Psw[l15 * PS_STRIDE + c * 32 + quad * 8]);
#pragma unroll
            for (int dt = 0; dt < 8; dt++) {
                bf16x8 vf = *(const bf16x8*)(&Vcur[((dt * 16 + l15) * 8 +
                                                    ((c * 4 + quad) ^ (l15 & 7))) * 8]);
                o_acc[dt] = __builtin_amdgcn_mfma_f32_16x16x32_bf16(pf, vf, o_acc[dt], 0, 0, 0);
            }
        }
    }

    // ---- finalize ---------------------------------------------------------
#pragma unroll
    for (int r = 0; r < 4; r++) {
        float l = l_part[r];
        l += __shfl_xor(l, 1, 64);
        l += __shfl_xor(l, 2, 64);
        l += __shfl_xor(l, 4, 64);
        l += __shfl_xor(l, 8, 64);
        float inv = 1.0f / l;
        int row = qrow + r;
        unsigned short* Op = O + (size_t)(b * S_LEN + row) * D_MODEL + h * DK;
#pragma unroll
        for (int dt = 0; dt < 8; dt++)
            Op[dt * 16 + l15] = f2bf(o_acc[dt][r] * inv);
    }
}

// ---------------- host ----------------
extern "C" void kernel_launch(void* const* d_in, const int* in_sizes, int n_in,
                              void* d_out, int out_size, void* d_ws, size_t ws_size,
                              hipStream_t stream) {
    const float* inp = (const float*)d_in[0];
    const float* wq  = (const float*)d_in[1];
    const float* wk  = (const float*)d_in[2];
    const float* wv  = (const float*)d_in[3];
    const float* wo  = (const float*)d_in[4];
    const float* bias = (const float*)d_in[5];
    const int* softcap = (const int*)d_in[6];
    float* out = (float*)d_out;

    unsigned short* ws = (unsigned short*)d_ws;
    const size_t n_inp = (size_t)NB * S_LEN * D_MODEL;
    const size_t n_w = (size_t)D_MODEL * D_MODEL;
    unsigned short* inp_b = ws;
    unsigned short* wq_b = inp_b + n_inp;
    unsigned short* wk_b = wq_b + n_w;
    unsigned short* wv_b = wk_b + n_w;
    unsigned short* wo_b = wv_b + n_w;
    unsigned short* Qb = wo_b + n_w;
    unsigned short* Kb = Qb + n_inp;
    unsigned short* Vtb = Kb + n_inp;   // [D_MODEL][NB*S_LEN] = V^T
    unsigned short* Ob = Vtb + n_inp;

    cast_f32_to_bf16<<<dim3(1024), dim3(256), 0, stream>>>(inp, inp_b, (int)(n_inp / 4));
    cast4_f32_to_bf16<<<dim3(256, 4), dim3(256), 0, stream>>>(
        wq, wk, wv, wo, wq_b, wk_b, wv_b, wo_b, (int)(n_w / 4));

    // fused Q+K projection: 1024 blocks = 4/CU
    gemm_qk<<<dim3(NB * S_LEN / BM, 2 * D_MODEL / BN), 256, 0, stream>>>(
        inp_b, wq_b, wk_b, Qb, Kb, NB * S_LEN, D_MODEL, D_MODEL);
    // V^T = Wv * X^T
    dim3 gv(D_MODEL / BM, NB * S_LEN / BN);  // (16, 32)
    gemm_bt<unsigned short><<<gv, 256, 0, stream>>>(wv_b, inp_b, Vtb, D_MODEL, NB * S_LEN, D_MODEL);

    flash_attn<<<dim3(S_LEN / QT, NH, NB), 512, 0, stream>>>(Qb, Kb, Vtb, bias, softcap, Ob);

    dim3 gg(NB * S_LEN / BM, D_MODEL / BN);  // (32, 16)
    gemm_bt<float><<<gg, 256, 0, stream>>>(Ob, wo_b, out, NB * S_LEN, D_MODEL, D_MODEL);
}